// Round 8
// baseline (57.054 us; speedup 1.0000x reference)
//
#include <hip/hip_runtime.h>
#include <stdint.h>

// IDs in [0, 100000): 100000 bits -> 3125 u32 words; pad to 3136 (x64) so
// every bitset slice is 16B-aligned for uint4 ops.
#define NWORDS 3125
#define NWP    3136
#define NVEC   (NWP / 4)              // 784 uint4 per bitset
#define SCAN_BLOCKS 1024
#define SCAN_THREADS 512
#define NPART  8                      // partial tail bitsets (collision spread)

// int4 with alignment relaxed to 4B: gfx950 supports dword-aligned dwordx4.
typedef int4 __attribute__((aligned(4))) int4_a4;

__global__ void zero_kernel(uint32_t* __restrict__ w, int n) {
    int i = blockIdx.x * blockDim.x + threadIdx.x;
    if (i < n) w[i] = 0u;
}

__global__ void build_hr_kernel(const int* __restrict__ neg, int B,
                                uint32_t* __restrict__ headb,
                                uint32_t* __restrict__ relb) {
    int b = blockIdx.x * blockDim.x + threadIdx.x;
    if (b >= B) return;
    int h = neg[b * 3 + 0];
    int r = neg[b * 3 + 1];
    atomicOr(&headb[h >> 5], 1u << (h & 31));
    atomicOr(&relb[r >> 5], 1u << (r & 31));
}

// Stream mapped_triples (overlapping 16B loads at 12B stride; h,r,t arrive in
// .x,.y,.z). 2-deep software pipeline: two independent loads in flight before
// either body runs -> halves exposed HBM latency. Branchless h&r test.
// Tails marked in per-block LDS bitset, flushed via global atomicOr into one
// of NPART partial bitsets (blockIdx&7), L2-resident.
__global__ __launch_bounds__(SCAN_THREADS, 8) void scan_triples_kernel(
        const int* __restrict__ mt, int N,
        const uint32_t* __restrict__ headb,
        const uint32_t* __restrict__ relb,
        uint32_t* __restrict__ parts) {
    __shared__ __align__(16) uint32_t sh[NWP];
    __shared__ __align__(16) uint32_t sr[NWP];
    __shared__ __align__(16) uint32_t st[NWP];

    uint4* sh4 = (uint4*)sh;
    uint4* sr4 = (uint4*)sr;
    uint4* st4 = (uint4*)st;
    const uint4* hb4 = (const uint4*)headb;
    const uint4* rb4 = (const uint4*)relb;
    for (int i = threadIdx.x; i < NVEC; i += blockDim.x) {
        sh4[i] = hb4[i];
        sr4[i] = rb4[i];
        st4[i] = make_uint4(0u, 0u, 0u, 0u);
    }
    __syncthreads();

    const uint32_t tid = blockIdx.x * blockDim.x + threadIdx.x;
    const uint32_t stride = gridDim.x * blockDim.x;
    const uint32_t lim = (uint32_t)(N - 1);  // last triple handled scalar
    const char* __restrict__ base = (const char*)mt;

#define BODY(V) do {                                                  \
        int h = (V).x, r = (V).y, t = (V).z;                          \
        uint32_t hbit = (sh[h >> 5] >> (h & 31)) & 1u;                \
        uint32_t rbit = (sr[r >> 5] >> (r & 31)) & 1u;                \
        if (hbit & rbit) {                                            \
            uint32_t bit = 1u << (t & 31);                            \
            if (!(st[t >> 5] & bit)) atomicOr(&st[t >> 5], bit);      \
        }                                                             \
    } while (0)

    uint32_t i = tid;
    // 2-deep: both loads issue before either body (independent addresses,
    // 32-bit byte offsets; max offset 192M < 2^31)
    for (; i + stride < lim; i += 2 * stride) {
        int4 v0 = *(const int4_a4*)(base + i * 12u);
        int4 v1 = *(const int4_a4*)(base + (i + stride) * 12u);
        BODY(v0);
        BODY(v1);
    }
    for (; i < lim; i += stride) {
        int4 v = *(const int4_a4*)(base + i * 12u);
        BODY(v);
    }
#undef BODY
    if (tid == 0) {  // last triple, scalar (no over-read)
        int h = mt[(size_t)(N - 1) * 3 + 0];
        int r = mt[(size_t)(N - 1) * 3 + 1];
        int t = mt[(size_t)(N - 1) * 3 + 2];
        if (((sh[h >> 5] >> (h & 31)) & 1u) && ((sr[r >> 5] >> (r & 31)) & 1u))
            atomicOr(&st[t >> 5], 1u << (t & 31));
    }

    __syncthreads();
    // flush nonzero words straight into one of NPART global partial bitsets
    uint32_t* dst = parts + (size_t)(blockIdx.x & (NPART - 1)) * NWP;
    for (int i2 = threadIdx.x; i2 < NWORDS; i2 += blockDim.x) {
        uint32_t v = st[i2];
        if (v) atomicOr(&dst[i2], v);
    }
}

__global__ void finalize_kernel(const int* __restrict__ neg, int B,
                                const uint32_t* __restrict__ parts,
                                int* __restrict__ out) {
    int b = blockIdx.x * blockDim.x + threadIdx.x;
    if (b >= B) return;
    int h = neg[b * 3 + 0];
    int r = neg[b * 3 + 1];
    int t = neg[b * 3 + 2];
    int w = t >> 5;
    uint32_t acc = 0u;
#pragma unroll
    for (int c = 0; c < NPART; ++c) acc |= parts[c * NWP + w];
    bool filtered = (acc >> (t & 31)) & 1u;
    int keep = filtered ? 0 : 1;
    out[b * 3 + 0] = keep ? h : -1;
    out[b * 3 + 1] = keep ? r : -1;
    out[b * 3 + 2] = keep ? t : -1;
    out[3 * B + b] = keep;  // keep_mask as 0/1 int32
}

extern "C" void kernel_launch(void* const* d_in, const int* in_sizes, int n_in,
                              void* d_out, int out_size, void* d_ws, size_t ws_size,
                              hipStream_t stream) {
    const int* neg = (const int*)d_in[0];   // [B,3] int32
    const int* mt  = (const int*)d_in[1];   // [N,3] int32
    int B = in_sizes[0] / 3;
    int N = in_sizes[1] / 3;
    int* out = (int*)d_out;

    uint32_t* ws    = (uint32_t*)d_ws;
    uint32_t* headb = ws;               // NWP
    uint32_t* relb  = ws + NWP;         // NWP
    uint32_t* parts = ws + 2 * NWP;     // NPART * NWP (~100 KB, L2-resident)

    // zero head/rel bitsets + partial tail bitsets (ws not re-poisoned
    // between replays — must re-zero every call)
    zero_kernel<<<((2 + NPART) * NWP + 255) / 256, 256, 0, stream>>>(
        ws, (2 + NPART) * NWP);
    build_hr_kernel<<<(B + 255) / 256, 256, 0, stream>>>(neg, B, headb, relb);
    scan_triples_kernel<<<SCAN_BLOCKS, SCAN_THREADS, 0, stream>>>(
        mt, N, headb, relb, parts);
    finalize_kernel<<<(B + 255) / 256, 256, 0, stream>>>(neg, B, parts, out);
}